// Round 2
// baseline (681.367 us; speedup 1.0000x reference)
//
#include <hip/hip_runtime.h>
#include <math.h>

#define B_ROWS   1024
#define IN_FEAT  76800
#define OUT_FEAT 10
#define NF4      (IN_FEAT / 4)        // 19200 float4 per row
#define W_ELEMS  (OUT_FEAT * IN_FEAT) // 768000
#define EPSQ     1e-5f
#define NREG     15                   // float4 cached in registers per thread (60 VGPRs)
#define NLDS     (NF4 - NREG * 1024)  // 3840 float4 in LDS (60 KB)

// ---------------- K1: per-block partial sums of |W| ----------------
__global__ __launch_bounds__(256) void k_wabs_partial(const float* __restrict__ W,
                                                      float* __restrict__ partials) {
    const int tid = threadIdx.x, bid = blockIdx.x;
    float s = 0.f;
    for (int i = bid * 256 + tid; i < W_ELEMS; i += 256 * 256) s += fabsf(W[i]);
    #pragma unroll
    for (int off = 32; off >= 1; off >>= 1) s += __shfl_down(s, off, 64);
    __shared__ float red[4];
    const int wv = tid >> 6, ln = tid & 63;
    if (ln == 0) red[wv] = s;
    __syncthreads();
    if (tid == 0) partials[bid] = red[0] + red[1] + red[2] + red[3];
}

// ---------------- K2: final reduce -> scale_w = 1/clip(mean|W|, eps) ----------------
__global__ __launch_bounds__(256) void k_wscale(const float* __restrict__ partials,
                                                float* __restrict__ scale_w) {
    const int tid = threadIdx.x;
    float s = partials[tid];
    #pragma unroll
    for (int off = 32; off >= 1; off >>= 1) s += __shfl_down(s, off, 64);
    __shared__ float red[4];
    const int wv = tid >> 6, ln = tid & 63;
    if (ln == 0) red[wv] = s;
    __syncthreads();
    if (tid == 0) {
        float mean = (red[0] + red[1] + red[2] + red[3]) / (float)W_ELEMS;
        scale_w[0] = 1.0f / fmaxf(mean, EPSQ);
    }
}

// ---------------- K3: ternary-quantize + transpose-pack weights ----------------
// wpack[k] bits [2o+1:2o] = round(W[o][k]*s_w) clamped to [-1,1], stored as code+1 in {0,1,2}
__global__ __launch_bounds__(256) void k_wpack(const float* __restrict__ W,
                                               const float* __restrict__ scale_w,
                                               unsigned int* __restrict__ wpack) {
    const int k = blockIdx.x * 256 + threadIdx.x;
    if (k >= IN_FEAT) return;
    const float s = scale_w[0];
    unsigned int u = 0;
    #pragma unroll
    for (int o = 0; o < OUT_FEAT; ++o) {
        float c = fminf(1.f, fmaxf(-1.f, rintf(W[o * IN_FEAT + k] * s)));
        u |= (unsigned int)((int)c + 1) << (2 * o);
    }
    wpack[k] = u;
}

// ---------------- main: one block per row, one-pass quant + GEMV + softmax ----------------
__device__ __forceinline__ void proc1(float xv, unsigned int w, float sx,
                                      float* acc, float& sq) {
    float q = rintf(xv * sx);   // |x*sx| <= 127*(1+2eps) -> rint in [-127,127], no clamp needed
    sq += q;
    #pragma unroll
    for (int o = 0; o < OUT_FEAT; ++o)
        acc[o] = fmaf(q, (float)((w >> (2 * o)) & 3u), acc[o]);
}

__device__ __forceinline__ void proc4(float4 v, uint4 w, float sx, float* acc, float& sq) {
    proc1(v.x, w.x, sx, acc, sq);
    proc1(v.y, w.y, sx, acc, sq);
    proc1(v.z, w.z, sx, acc, sq);
    proc1(v.w, w.w, sx, acc, sq);
}

// block=1024 (16 waves): min 4 waves/EU = 1 block/CU -> VGPR cap 128, room for the
// 60-VGPR xr[] cache without spilling (R1: launch_bounds(1024) alone capped at 64
// VGPRs -> 734 MB of scratch spill writes).
__global__ __launch_bounds__(1024, 4) void k_main(const float* __restrict__ x,
                                                  const unsigned int* __restrict__ wpack,
                                                  const float* __restrict__ bias,
                                                  const float* __restrict__ scale_w,
                                                  float* __restrict__ out) {
    __shared__ float4 xlds[NLDS];        // 60 KB row cache
    __shared__ float  redmax[16];
    __shared__ float  racc[16][12];
    __shared__ float  fin[12];
    __shared__ float  lgs[OUT_FEAT];
    __shared__ float  sx_sh;

    const int tid = threadIdx.x;
    const int row = blockIdx.x;
    const float sw = scale_w[0];
    const float4* __restrict__ xrow = (const float4*)(x + (size_t)row * IN_FEAT);

    // ---- phase 1: load row into regs + LDS, compute absmax ----
    float4 xr[NREG];
    float mx = 0.f;
    #pragma unroll
    for (int j = 0; j < NREG; ++j) {
        float4 v = xrow[tid + j * 1024];
        xr[j] = v;
        mx = fmaxf(mx, fmaxf(fmaxf(fabsf(v.x), fabsf(v.y)), fmaxf(fabsf(v.z), fabsf(v.w))));
    }
    #pragma unroll
    for (int j = NREG; j < 19; ++j) {
        int idx = tid + j * 1024;
        if (idx < NF4) {
            float4 v = xrow[idx];
            xlds[idx - NREG * 1024] = v;
            mx = fmaxf(mx, fmaxf(fmaxf(fabsf(v.x), fabsf(v.y)), fmaxf(fabsf(v.z), fabsf(v.w))));
        }
    }
    #pragma unroll
    for (int off = 32; off >= 1; off >>= 1) mx = fmaxf(mx, __shfl_down(mx, off, 64));
    const int wv = tid >> 6, ln = tid & 63;
    if (ln == 0) redmax[wv] = mx;
    __syncthreads();
    if (tid == 0) {
        float m = redmax[0];
        #pragma unroll
        for (int i = 1; i < 16; ++i) m = fmaxf(m, redmax[i]);
        sx_sh = 127.0f / fmaxf(m, EPSQ);
    }
    __syncthreads();
    const float sx = sx_sh;

    // ---- phase 2: quantize + ternary GEMV (acc[o] = sum qx*code, code in {0,1,2}) ----
    float acc[OUT_FEAT] = {0.f, 0.f, 0.f, 0.f, 0.f, 0.f, 0.f, 0.f, 0.f, 0.f};
    float sq = 0.f;
    const uint4* __restrict__ wp4 = (const uint4*)wpack;
    #pragma unroll
    for (int j = 0; j < NREG; ++j) {
        uint4 w = wp4[tid + j * 1024];
        proc4(xr[j], w, sx, acc, sq);
    }
    #pragma unroll
    for (int j = NREG; j < 19; ++j) {
        int idx = tid + j * 1024;
        if (idx < NF4) {
            uint4  w = wp4[idx];
            float4 v = xlds[idx - NREG * 1024];
            proc4(v, w, sx, acc, sq);
        }
    }

    // ---- phase 3: block reduce 11 values (10 accs + sum_q) ----
    float vals[11];
    #pragma unroll
    for (int t = 0; t < OUT_FEAT; ++t) vals[t] = acc[t];
    vals[10] = sq;
    #pragma unroll
    for (int t = 0; t < 11; ++t) {
        #pragma unroll
        for (int off = 32; off >= 1; off >>= 1) vals[t] += __shfl_down(vals[t], off, 64);
    }
    if (ln == 0) {
        #pragma unroll
        for (int t = 0; t < 11; ++t) racc[wv][t] = vals[t];
    }
    __syncthreads();
    if (tid < 11) {
        float s = 0.f;
        #pragma unroll
        for (int w2 = 0; w2 < 16; ++w2) s += racc[w2][tid];
        fin[tid] = s;
    }
    __syncthreads();
    if (tid < OUT_FEAT) {
        // sum qx*(code-1) = sum qx*code - sum qx ; dequant by 1/(sx*sw)
        float inv = 1.0f / (sx * sw);
        lgs[tid] = (fin[tid] - fin[10]) * inv + bias[tid];
    }
    __syncthreads();
    if (tid < OUT_FEAT) {
        float m = lgs[0];
        #pragma unroll
        for (int o = 1; o < OUT_FEAT; ++o) m = fmaxf(m, lgs[o]);
        float den = 0.f;
        #pragma unroll
        for (int o = 0; o < OUT_FEAT; ++o) den += __expf(lgs[o] - m);
        float e = __expf(lgs[tid] - m);
        out[row * OUT_FEAT + tid] = e / den;
    }
}

extern "C" void kernel_launch(void* const* d_in, const int* in_sizes, int n_in,
                              void* d_out, int out_size, void* d_ws, size_t ws_size,
                              hipStream_t stream) {
    const float* x    = (const float*)d_in[0];
    const float* Wmat = (const float*)d_in[1];
    const float* bias = (const float*)d_in[2];
    float* out = (float*)d_out;

    char* wsb = (char*)d_ws;
    float* scale_w        = (float*)wsb;                 // 1 float
    float* partials       = (float*)(wsb + 256);         // 256 floats
    unsigned int* wpack   = (unsigned int*)(wsb + 4096); // 76800 uint32 = 307 KB

    k_wabs_partial<<<256, 256, 0, stream>>>(Wmat, partials);
    k_wscale<<<1, 256, 0, stream>>>(partials, scale_w);
    k_wpack<<<(IN_FEAT + 255) / 256, 256, 0, stream>>>(Wmat, scale_w, wpack);
    k_main<<<B_ROWS, 1024, 0, stream>>>(x, wpack, bias, scale_w, out);
}

// Round 4
// 483.950 us; speedup vs baseline: 1.4079x; 1.4079x over previous
//
#include <hip/hip_runtime.h>
#include <math.h>

#define B_ROWS   1024
#define IN_FEAT  76800
#define OUT_FEAT 10
#define NF4      (IN_FEAT / 4)        // 19200 float4 per row
#define W_ELEMS  (OUT_FEAT * IN_FEAT) // 768000
#define EPSQ     1e-5f
#define NLDS     3840                 // float4 cached in LDS (60 KB = first 20% of row)

// ---------------- K1: per-block partial sums of |W| ----------------
__global__ __launch_bounds__(256) void k_wabs_partial(const float* __restrict__ W,
                                                      float* __restrict__ partials) {
    const int tid = threadIdx.x, bid = blockIdx.x;
    float s = 0.f;
    for (int i = bid * 256 + tid; i < W_ELEMS; i += 256 * 256) s += fabsf(W[i]);
    #pragma unroll
    for (int off = 32; off >= 1; off >>= 1) s += __shfl_down(s, off, 64);
    __shared__ float red[4];
    const int wv = tid >> 6, ln = tid & 63;
    if (ln == 0) red[wv] = s;
    __syncthreads();
    if (tid == 0) partials[bid] = red[0] + red[1] + red[2] + red[3];
}

// ---------------- K2: final reduce -> scale_w = 1/clip(mean|W|, eps) ----------------
__global__ __launch_bounds__(256) void k_wscale(const float* __restrict__ partials,
                                                float* __restrict__ scale_w) {
    const int tid = threadIdx.x;
    float s = partials[tid];
    #pragma unroll
    for (int off = 32; off >= 1; off >>= 1) s += __shfl_down(s, off, 64);
    __shared__ float red[4];
    const int wv = tid >> 6, ln = tid & 63;
    if (ln == 0) red[wv] = s;
    __syncthreads();
    if (tid == 0) {
        float mean = (red[0] + red[1] + red[2] + red[3]) / (float)W_ELEMS;
        scale_w[0] = 1.0f / fmaxf(mean, EPSQ);
    }
}

// ---------------- K3: ternary-quantize + transpose-pack weights ----------------
// wpack[k] bits [2o+1:2o] = round(W[o][k]*s_w) clamped to [-1,1], stored as code+1 in {0,1,2}
__global__ __launch_bounds__(256) void k_wpack(const float* __restrict__ W,
                                               const float* __restrict__ scale_w,
                                               unsigned int* __restrict__ wpack) {
    const int k = blockIdx.x * 256 + threadIdx.x;
    if (k >= IN_FEAT) return;
    const float s = scale_w[0];
    unsigned int u = 0;
    #pragma unroll
    for (int o = 0; o < OUT_FEAT; ++o) {
        float c = fminf(1.f, fmaxf(-1.f, rintf(W[o * IN_FEAT + k] * s)));
        u |= (unsigned int)((int)c + 1) << (2 * o);
    }
    wpack[k] = u;
}

// ---------------- main: one block per row, two-phase (absmax, then GEMV) ----------------
// Phase-2 x re-read is served by L3: 256 in-flight rows = ~77 MB << 256 MB Infinity
// Cache, so a row is still cache-resident when its block re-reads it. No register
// caching -> default 64-VGPR allocation, no spill, no occupancy attributes.
// (R1/R2: 60-VGPR reg cache spilled under the 64-VGPR cap -> 716 MB scratch writes;
//  R3: amdgpu_waves_per_eu(4,4) produced wrong results after graph replay — dropped.)
__device__ __forceinline__ void proc1(float xv, unsigned int w, float sx,
                                      float* acc, float& sq) {
    float q = rintf(xv * sx);   // |x*sx| <= 127*(1+2eps) -> rint in [-127,127], no clamp needed
    sq += q;
    #pragma unroll
    for (int o = 0; o < OUT_FEAT; ++o)
        acc[o] = fmaf(q, (float)((w >> (2 * o)) & 3u), acc[o]);
}

__device__ __forceinline__ void proc4(float4 v, uint4 w, float sx, float* acc, float& sq) {
    proc1(v.x, w.x, sx, acc, sq);
    proc1(v.y, w.y, sx, acc, sq);
    proc1(v.z, w.z, sx, acc, sq);
    proc1(v.w, w.w, sx, acc, sq);
}

__global__ __launch_bounds__(1024) void k_main(const float* __restrict__ x,
                                               const unsigned int* __restrict__ wpack,
                                               const float* __restrict__ bias,
                                               const float* __restrict__ scale_w,
                                               float* __restrict__ out) {
    __shared__ float4 xlds[NLDS];        // 60 KB cache of the row's first 3840 float4s
    __shared__ float  redmax[16];
    __shared__ float  racc[16][12];
    __shared__ float  fin[12];
    __shared__ float  lgs[OUT_FEAT];
    __shared__ float  sx_sh;

    const int tid = threadIdx.x;
    const int row = blockIdx.x;
    const float sw = scale_w[0];
    const float4* __restrict__ xrow = (const float4*)(x + (size_t)row * IN_FEAT);

    // ---- phase 1: stream row, compute absmax, cache first 60 KB in LDS ----
    float mx = 0.f;
    #pragma unroll
    for (int j = 0; j < 19; ++j) {
        int idx = tid + j * 1024;
        if (idx < NF4) {
            float4 v = xrow[idx];
            if (idx < NLDS) xlds[idx] = v;
            mx = fmaxf(mx, fmaxf(fmaxf(fabsf(v.x), fabsf(v.y)), fmaxf(fabsf(v.z), fabsf(v.w))));
        }
    }
    #pragma unroll
    for (int off = 32; off >= 1; off >>= 1) mx = fmaxf(mx, __shfl_down(mx, off, 64));
    const int wv = tid >> 6, ln = tid & 63;
    if (ln == 0) redmax[wv] = mx;
    __syncthreads();
    if (tid == 0) {
        float m = redmax[0];
        #pragma unroll
        for (int i = 1; i < 16; ++i) m = fmaxf(m, redmax[i]);
        sx_sh = 127.0f / fmaxf(m, EPSQ);
    }
    __syncthreads();
    const float sx = sx_sh;

    // ---- phase 2: re-read row (LDS for first 20%, L3 for the rest), quantize + GEMV ----
    float acc[OUT_FEAT] = {0.f, 0.f, 0.f, 0.f, 0.f, 0.f, 0.f, 0.f, 0.f, 0.f};
    float sq = 0.f;
    const uint4* __restrict__ wp4 = (const uint4*)wpack;
    #pragma unroll
    for (int j = 0; j < 19; ++j) {
        int idx = tid + j * 1024;
        if (idx < NF4) {
            uint4  w = wp4[idx];
            float4 v = (idx < NLDS) ? xlds[idx] : xrow[idx];
            proc4(v, w, sx, acc, sq);
        }
    }

    // ---- phase 3: block reduce 11 values (10 accs + sum_q) ----
    float vals[11];
    #pragma unroll
    for (int t = 0; t < OUT_FEAT; ++t) vals[t] = acc[t];
    vals[10] = sq;
    #pragma unroll
    for (int t = 0; t < 11; ++t) {
        #pragma unroll
        for (int off = 32; off >= 1; off >>= 1) vals[t] += __shfl_down(vals[t], off, 64);
    }
    if (ln == 0) {
        #pragma unroll
        for (int t = 0; t < 11; ++t) racc[wv][t] = vals[t];
    }
    __syncthreads();
    if (tid < 11) {
        float s = 0.f;
        #pragma unroll
        for (int w2 = 0; w2 < 16; ++w2) s += racc[w2][tid];
        fin[tid] = s;
    }
    __syncthreads();
    if (tid < OUT_FEAT) {
        // sum qx*(code-1) = sum qx*code - sum qx ; dequant by 1/(sx*sw)
        float inv = 1.0f / (sx * sw);
        lgs[tid] = (fin[tid] - fin[10]) * inv + bias[tid];
    }
    __syncthreads();
    if (tid < OUT_FEAT) {
        float m = lgs[0];
        #pragma unroll
        for (int o = 1; o < OUT_FEAT; ++o) m = fmaxf(m, lgs[o]);
        float den = 0.f;
        #pragma unroll
        for (int o = 0; o < OUT_FEAT; ++o) den += __expf(lgs[o] - m);
        float e = __expf(lgs[tid] - m);
        out[row * OUT_FEAT + tid] = e / den;
    }
}

extern "C" void kernel_launch(void* const* d_in, const int* in_sizes, int n_in,
                              void* d_out, int out_size, void* d_ws, size_t ws_size,
                              hipStream_t stream) {
    const float* x    = (const float*)d_in[0];
    const float* Wmat = (const float*)d_in[1];
    const float* bias = (const float*)d_in[2];
    float* out = (float*)d_out;

    char* wsb = (char*)d_ws;
    float* scale_w        = (float*)wsb;                 // 1 float
    float* partials       = (float*)(wsb + 256);         // 256 floats
    unsigned int* wpack   = (unsigned int*)(wsb + 4096); // 76800 uint32 = 307 KB

    k_wabs_partial<<<256, 256, 0, stream>>>(Wmat, partials);
    k_wscale<<<1, 256, 0, stream>>>(partials, scale_w);
    k_wpack<<<(IN_FEAT + 255) / 256, 256, 0, stream>>>(Wmat, scale_w, wpack);
    k_main<<<B_ROWS, 1024, 0, stream>>>(x, wpack, bias, scale_w, out);
}